// Round 1
// baseline (355.630 us; speedup 1.0000x reference)
//
#include <hip/hip_runtime.h>
#include <hip/hip_bf16.h>

#define TSEQ 2048
#define NB 4
#define NH 12
#define CDIM 768
#define LDQKV 2304

typedef short bf16x8 __attribute__((ext_vector_type(8)));
typedef float f32x4 __attribute__((ext_vector_type(4)));

__device__ __forceinline__ short f2bf(float f) {
  union { float f; unsigned u; } x; x.f = f;
  unsigned r = x.u + 0x7fffu + ((x.u >> 16) & 1u);  // RNE
  return (short)(r >> 16);
}

__device__ __forceinline__ void gload_lds16(const void* g, void* lds) {
  __builtin_amdgcn_global_load_lds(
      (const __attribute__((address_space(1))) void*)g,
      (__attribute__((address_space(3))) void*)lds, 16, 0, 0);
}

__global__ __launch_bounds__(256) void cast_bf16_kernel(
    const float* __restrict__ in, short* __restrict__ out, int n4) {
  int i = blockIdx.x * 256 + threadIdx.x;
  const int stride = gridDim.x * 256;
  for (; i < n4; i += stride) {
    float4 v = reinterpret_cast<const float4*>(in)[i];
    short4 r = make_short4(f2bf(v.x), f2bf(v.y), f2bf(v.z), f2bf(v.w));
    reinterpret_cast<short4*>(out)[i] = r;
  }
}

// C[M,N] = A[M,K] * B[N,K]^T + bias.  A,B bf16(short) row-major, bias fp32.
// m97 structure: 128x128 tile, BK=32, 4 waves (2x2), global_load_lds width 16.
template<int OUTBF>
__global__ __launch_bounds__(256) void gemm_bt_kernel(
    const short* __restrict__ A, const short* __restrict__ B,
    const float* __restrict__ bias, void* __restrict__ C,
    int M, int N, int K) {
  __shared__ __align__(16) short As[128 * 32];
  __shared__ __align__(16) short Bs[128 * 32];
  const int tid = threadIdx.x;
  const int w = tid >> 6, l = tid & 63;
  const int lr = l & 15, lk = l >> 4;
  const int bm = blockIdx.x * 128, bn = blockIdx.y * 128;
  const int wr = (w >> 1) * 64, wc = (w & 1) * 64;
  const int srow = tid >> 2, scol = (tid & 3) * 8;  // staging: row=tid/4, 8 elems at (tid%4)*8

  const short* Ag = A + (long)(bm + srow) * K + scol;
  const short* Bg = B + (long)(bn + srow) * K + scol;
  short* AsW = As + w * 512;  // wave-uniform LDS base; HW scatters lane*16B
  short* BsW = Bs + w * 512;

  f32x4 acc[4][4] = {};

  for (int kk = 0; kk < K; kk += 32) {
    gload_lds16(Ag + kk, AsW);                       // rows 0..63
    gload_lds16(Ag + (long)64 * K + kk, AsW + 2048); // rows 64..127
    gload_lds16(Bg + kk, BsW);
    gload_lds16(Bg + (long)64 * K + kk, BsW + 2048);
    __syncthreads();  // drains vmcnt -> LDS valid
    bf16x8 af[4], bfr[4];
#pragma unroll
    for (int m = 0; m < 4; ++m)
      af[m] = *reinterpret_cast<const bf16x8*>(As + (wr + m * 16 + lr) * 32 + lk * 8);
#pragma unroll
    for (int n = 0; n < 4; ++n)
      bfr[n] = *reinterpret_cast<const bf16x8*>(Bs + (wc + n * 16 + lr) * 32 + lk * 8);
#pragma unroll
    for (int m = 0; m < 4; ++m)
#pragma unroll
      for (int n = 0; n < 4; ++n)
        acc[m][n] = __builtin_amdgcn_mfma_f32_16x16x32_bf16(af[m], bfr[n], acc[m][n], 0, 0, 0);
    __syncthreads();
  }

  float bv[4];
#pragma unroll
  for (int n = 0; n < 4; ++n) bv[n] = bias[bn + wc + n * 16 + lr];
#pragma unroll
  for (int m = 0; m < 4; ++m) {
    const int row0 = bm + wr + m * 16 + lk * 4;  // C/D: row=(l>>4)*4+reg, col=l&15
#pragma unroll
    for (int n = 0; n < 4; ++n) {
      const int col = bn + wc + n * 16 + lr;
#pragma unroll
      for (int j = 0; j < 4; ++j) {
        float v = acc[m][n][j] + bv[n];
        if (OUTBF) reinterpret_cast<short*>(C)[(long)(row0 + j) * N + col] = f2bf(v);
        else       reinterpret_cast<float*>(C)[(long)(row0 + j) * N + col] = v;
      }
    }
  }
}

// Flash attention, causal. qkv rows [b*2048+t][2304]; split order is K,Q,V.
// Block: 64 q-rows (4 waves x 16), KV tiles of 64. logits = 0.25 * q.k (SDPA double-add).
__global__ __launch_bounds__(256) void attn_kernel(
    const short* __restrict__ qkv, short* __restrict__ y) {
  __shared__ __align__(16) short Ks[64 * 72];       // [kcol][d], padded 64->72 vs bank conflicts
  __shared__ __align__(16) short Vt[64 * 72];       // [d][kcol] (transposed)
  __shared__ __align__(16) short Ps[4 * 16 * 72];   // per-wave P tile [16 q][64 k]
  const int tid = threadIdx.x;
  const int w = tid >> 6, l = tid & 63;
  const int lr = l & 15, lk = l >> 4;
  const int qt = blockIdx.x & 31;
  const int bh = blockIdx.x >> 5;
  const int b = bh / NH, h = bh % NH;
  const short* base = qkv + (long)b * TSEQ * LDQKV;
  const int kcol = h * 64, qcol = CDIM + h * 64, vcol = 2 * CDIM + h * 64;

  const int qrow = qt * 64 + w * 16 + lr;
  bf16x8 qf0 = *reinterpret_cast<const bf16x8*>(base + (long)qrow * LDQKV + qcol + lk * 8);
  bf16x8 qf1 = *reinterpret_cast<const bf16x8*>(base + (long)qrow * LDQKV + qcol + 32 + lk * 8);

  float m[4], lsum[4];
  f32x4 o[4] = {};
#pragma unroll
  for (int j = 0; j < 4; ++j) { m[j] = -1e30f; lsum[j] = 0.f; }

  const int srow = tid >> 2, scol = (tid & 3) * 16;
  short* PsW = Ps + w * (16 * 72);

  for (int kt = 0; kt <= qt; ++kt) {
    __syncthreads();
    {
      const short* kg = base + (long)(kt * 64 + srow) * LDQKV + kcol + scol;
      *reinterpret_cast<bf16x8*>(Ks + srow * 72 + scol)     = *reinterpret_cast<const bf16x8*>(kg);
      *reinterpret_cast<bf16x8*>(Ks + srow * 72 + scol + 8) = *reinterpret_cast<const bf16x8*>(kg + 8);
      const short* vg = base + (long)(kt * 64 + srow) * LDQKV + vcol + scol;
      bf16x8 v0 = *reinterpret_cast<const bf16x8*>(vg);
      bf16x8 v1 = *reinterpret_cast<const bf16x8*>(vg + 8);
#pragma unroll
      for (int j2 = 0; j2 < 8; ++j2) Vt[(scol + j2) * 72 + srow] = v0[j2];
#pragma unroll
      for (int j2 = 0; j2 < 8; ++j2) Vt[(scol + 8 + j2) * 72 + srow] = v1[j2];
    }
    __syncthreads();

    // S = Q K^T : 4 col-frags x 2 K-steps
    f32x4 sc[4];
#pragma unroll
    for (int n = 0; n < 4; ++n) {
      bf16x8 kb0 = *reinterpret_cast<const bf16x8*>(Ks + (n * 16 + lr) * 72 + lk * 8);
      bf16x8 kb1 = *reinterpret_cast<const bf16x8*>(Ks + (n * 16 + lr) * 72 + 32 + lk * 8);
      f32x4 z = {};
      z = __builtin_amdgcn_mfma_f32_16x16x32_bf16(qf0, kb0, z, 0, 0, 0);
      sc[n] = __builtin_amdgcn_mfma_f32_16x16x32_bf16(qf1, kb1, z, 0, 0, 0);
    }

    const bool diag = (kt == qt);
#pragma unroll
    for (int n = 0; n < 4; ++n) {
#pragma unroll
      for (int j = 0; j < 4; ++j) {
        float v = sc[n][j] * 0.25f;
        if (diag && (n * 16 + lr) > (w * 16 + lk * 4 + j)) v = -1e30f;
        sc[n][j] = v;
      }
    }

    // online softmax: row r lives in 16-lane group (r>>2), reg r&3
    float alpha[4];
#pragma unroll
    for (int j = 0; j < 4; ++j) {
      float rm = fmaxf(fmaxf(sc[0][j], sc[1][j]), fmaxf(sc[2][j], sc[3][j]));
#pragma unroll
      for (int off = 1; off < 16; off <<= 1)
        rm = fmaxf(rm, __shfl_xor(rm, off));
      float mn = fmaxf(m[j], rm);
      alpha[j] = __expf(m[j] - mn);
      m[j] = mn;
      float rs = 0.f;
#pragma unroll
      for (int n = 0; n < 4; ++n) {
        float p = __expf(sc[n][j] - mn);
        PsW[(lk * 4 + j) * 72 + n * 16 + lr] = f2bf(p);
        rs += p;
      }
#pragma unroll
      for (int off = 1; off < 16; off <<= 1)
        rs += __shfl_xor(rs, off);
      lsum[j] = lsum[j] * alpha[j] + rs;
    }
#pragma unroll
    for (int n = 0; n < 4; ++n) {
      o[n][0] *= alpha[0]; o[n][1] *= alpha[1]; o[n][2] *= alpha[2]; o[n][3] *= alpha[3];
    }

    // PV: A=P (from LDS), B=V via Vt rows
    bf16x8 pa0 = *reinterpret_cast<const bf16x8*>(PsW + lr * 72 + lk * 8);
    bf16x8 pa1 = *reinterpret_cast<const bf16x8*>(PsW + lr * 72 + 32 + lk * 8);
#pragma unroll
    for (int n = 0; n < 4; ++n) {
      bf16x8 vb0 = *reinterpret_cast<const bf16x8*>(Vt + (n * 16 + lr) * 72 + lk * 8);
      bf16x8 vb1 = *reinterpret_cast<const bf16x8*>(Vt + (n * 16 + lr) * 72 + 32 + lk * 8);
      o[n] = __builtin_amdgcn_mfma_f32_16x16x32_bf16(pa0, vb0, o[n], 0, 0, 0);
      o[n] = __builtin_amdgcn_mfma_f32_16x16x32_bf16(pa1, vb1, o[n], 0, 0, 0);
    }
  }

  float inv[4];
#pragma unroll
  for (int j = 0; j < 4; ++j) inv[j] = 1.0f / lsum[j];
#pragma unroll
  for (int n = 0; n < 4; ++n) {
#pragma unroll
    for (int j = 0; j < 4; ++j) {
      const int row = qt * 64 + w * 16 + lk * 4 + j;
      const int col = h * 64 + n * 16 + lr;
      y[(long)(b * TSEQ + row) * CDIM + col] = f2bf(o[n][j] * inv[j]);
    }
  }
}

extern "C" void kernel_launch(void* const* d_in, const int* in_sizes, int n_in,
                              void* d_out, int out_size, void* d_ws, size_t ws_size,
                              hipStream_t stream) {
  const float* x      = (const float*)d_in[0];
  const float* w_attn = (const float*)d_in[1];
  const float* b_attn = (const float*)d_in[2];
  const float* w_proj = (const float*)d_in[3];
  const float* b_proj = (const float*)d_in[4];
  float* out = (float*)d_out;

  // ws layout (bytes): Xb 12.58M | Wab 3.54M | Wpb 1.18M | QKVb 37.75M | Yb 12.58M  (~64.5 MiB)
  char* ws = (char*)d_ws;
  short* Xb   = (short*)(ws);
  short* Wab  = (short*)(ws + 12582912);
  short* Wpb  = (short*)(ws + 16121856);
  short* QKVb = (short*)(ws + 17301504);
  short* Yb   = (short*)(ws + 55050240);

  cast_bf16_kernel<<<2048, 256, 0, stream>>>(x,      Xb,  (NB * TSEQ * CDIM) / 4);
  cast_bf16_kernel<<<1728, 256, 0, stream>>>(w_attn, Wab, (3 * CDIM * CDIM) / 4);
  cast_bf16_kernel<<<576,  256, 0, stream>>>(w_proj, Wpb, (CDIM * CDIM) / 4);

  // qkv = x @ w_attn^T + b_attn  -> bf16 [8192][2304]
  gemm_bt_kernel<1><<<dim3(64, 18), 256, 0, stream>>>(Xb, Wab, b_attn, QKVb, 8192, 2304, 768);
  // flash attention -> Yb bf16 [8192][768]
  attn_kernel<<<NB * NH * 32, 256, 0, stream>>>(QKVb, Yb);
  // out = y @ w_proj^T + b_proj  -> fp32
  gemm_bt_kernel<0><<<dim3(64, 6), 256, 0, stream>>>(Yb, Wpb, b_proj, out, 8192, 768, 768);
}

// Round 2
// 313.758 us; speedup vs baseline: 1.1335x; 1.1335x over previous
//
#include <hip/hip_runtime.h>
#include <hip/hip_bf16.h>

#define TSEQ 2048
#define NB 4
#define NH 12
#define CDIM 768
#define LDQKV 2304

typedef short bf16x8 __attribute__((ext_vector_type(8)));
typedef float f32x4 __attribute__((ext_vector_type(4)));

__device__ __forceinline__ short f2bf(float f) {
  union { float f; unsigned u; } x; x.f = f;
  unsigned r = x.u + 0x7fffu + ((x.u >> 16) & 1u);  // RNE
  return (short)(r >> 16);
}

__device__ __forceinline__ void gload_lds16(const void* g, void* lds) {
  __builtin_amdgcn_global_load_lds(
      (const __attribute__((address_space(1))) void*)g,
      (__attribute__((address_space(3))) void*)lds, 16, 0, 0);
}

__global__ __launch_bounds__(256) void cast_bf16_kernel(
    const float* __restrict__ in, short* __restrict__ out, int n4) {
  int i = blockIdx.x * 256 + threadIdx.x;
  const int stride = gridDim.x * 256;
  for (; i < n4; i += stride) {
    float4 v = reinterpret_cast<const float4*>(in)[i];
    short4 r = make_short4(f2bf(v.x), f2bf(v.y), f2bf(v.z), f2bf(v.w));
    reinterpret_cast<short4*>(out)[i] = r;
  }
}

// C[M,N] = A[M,K] * B[N,K]^T + bias.  m97 structure + bijective XCD swizzle.
template<int OUTBF>
__global__ __launch_bounds__(256) void gemm_bt_kernel(
    const short* __restrict__ A, const short* __restrict__ B,
    const float* __restrict__ bias, void* __restrict__ C,
    int M, int N, int K) {
  __shared__ __align__(16) short As[128 * 32];
  __shared__ __align__(16) short Bs[128 * 32];
  const int tid = threadIdx.x;
  const int w = tid >> 6, l = tid & 63;
  const int lr = l & 15, lk = l >> 4;
  // XCD-aware swizzle (nwg % 8 == 0 for both GEMMs)
  const int nwg = gridDim.x * gridDim.y;
  const int wg = blockIdx.y * gridDim.x + blockIdx.x;
  const int swz = (wg & 7) * (nwg >> 3) + (wg >> 3);
  const int bm = (swz % gridDim.x) * 128, bn = (swz / gridDim.x) * 128;
  const int wr = (w >> 1) * 64, wc = (w & 1) * 64;
  const int srow = tid >> 2, scol = (tid & 3) * 8;

  const short* Ag = A + (long)(bm + srow) * K + scol;
  const short* Bg = B + (long)(bn + srow) * K + scol;
  short* AsW = As + w * 512;
  short* BsW = Bs + w * 512;

  f32x4 acc[4][4] = {};

  for (int kk = 0; kk < K; kk += 32) {
    gload_lds16(Ag + kk, AsW);
    gload_lds16(Ag + (long)64 * K + kk, AsW + 2048);
    gload_lds16(Bg + kk, BsW);
    gload_lds16(Bg + (long)64 * K + kk, BsW + 2048);
    __syncthreads();
    bf16x8 af[4], bfr[4];
#pragma unroll
    for (int m = 0; m < 4; ++m)
      af[m] = *reinterpret_cast<const bf16x8*>(As + (wr + m * 16 + lr) * 32 + lk * 8);
#pragma unroll
    for (int n = 0; n < 4; ++n)
      bfr[n] = *reinterpret_cast<const bf16x8*>(Bs + (wc + n * 16 + lr) * 32 + lk * 8);
#pragma unroll
    for (int m = 0; m < 4; ++m)
#pragma unroll
      for (int n = 0; n < 4; ++n)
        acc[m][n] = __builtin_amdgcn_mfma_f32_16x16x32_bf16(af[m], bfr[n], acc[m][n], 0, 0, 0);
    __syncthreads();
  }

  float bv[4];
#pragma unroll
  for (int n = 0; n < 4; ++n) bv[n] = bias[bn + wc + n * 16 + lr];
#pragma unroll
  for (int m = 0; m < 4; ++m) {
    const int row0 = bm + wr + m * 16 + lk * 4;
#pragma unroll
    for (int n = 0; n < 4; ++n) {
      const int col = bn + wc + n * 16 + lr;
#pragma unroll
      for (int j = 0; j < 4; ++j) {
        float v = acc[m][n][j] + bv[n];
        if (OUTBF) reinterpret_cast<short*>(C)[(long)(row0 + j) * N + col] = f2bf(v);
        else       reinterpret_cast<float*>(C)[(long)(row0 + j) * N + col] = v;
      }
    }
  }
}

// Flash attention v2: swapped QK^T (S^T = mfma(K,Q)), K double-buffered via
// swizzled-source global_load_lds, V/P packed b32 with quad-XOR swizzle,
// raw barriers (no vmcnt(0) drain in loop). Split order in qkv is K,Q,V.
__global__ __launch_bounds__(256) void attn_kernel(
    const short* __restrict__ qkv, short* __restrict__ y) {
  __shared__ __align__(16) short    Ks[2][64 * 64];      // XOR-swizzled rows (128B)
  __shared__ __align__(16) unsigned Vt32[64][36];        // V^T, k-pair packed, quad-XOR
  __shared__ __align__(16) unsigned Ps32[4][16][36];     // per-wave P, same packing
  const int tid = threadIdx.x;
  const int w = tid >> 6, l = tid & 63;
  const int lr = l & 15, lk = l >> 4;
  const int qt = blockIdx.x & 31;
  const int bh = blockIdx.x >> 5;
  const int b = bh / NH, h = bh % NH;
  const short* base = qkv + (long)b * TSEQ * LDQKV;
  const int kcol = h * 64, qcol = CDIM + h * 64, vcol = 2 * CDIM + h * 64;

  // Q fragments (B-operand of swapped QK^T)
  const int qrow = qt * 64 + w * 16 + lr;
  bf16x8 qf0 = *reinterpret_cast<const bf16x8*>(base + (long)qrow * LDQKV + qcol + lk * 8);
  bf16x8 qf1 = *reinterpret_cast<const bf16x8*>(base + (long)qrow * LDQKV + qcol + 32 + lk * 8);

  // K staging geometry: lane covers LDS 16B-slot (l&7) of row (l>>3); source
  // col pre-swizzled so LDS holds row-major ^ ((row&7)<<4).
  const int krow = w * 16 + (l >> 3);
  const int kc16 = (((l & 7) ^ (l >> 3)) * 8);
  // V staging: thread loads k rows {vkr, vkr+1}, d cols vdc..vdc+7
  const int vkr = (tid >> 3) * 2;
  const int vdc = (tid & 7) * 8;
  const int vc = tid >> 3;                       // k-pair index
  const int vcol_sw = 4 * ((vc >> 2) ^ (tid & 7)) + (vc & 3);  // (d>>3)&7 == tid&7

  float m = -1e30f, lsum = 0.f;
  f32x4 o[4] = {};

  int cur = 0;
  {
    const short* kg = base + (long)krow * LDQKV + kcol + kc16;
    gload_lds16(kg, &Ks[0][(w * 16) * 64]);
    gload_lds16(kg + (long)8 * LDQKV, &Ks[0][(w * 16 + 8) * 64]);
  }
  __builtin_amdgcn_sched_barrier(0);  // keep K issue before V-reg loads
  bf16x8 va = *reinterpret_cast<const bf16x8*>(base + (long)vkr * LDQKV + vcol + vdc);
  bf16x8 vb = *reinterpret_cast<const bf16x8*>(base + (long)(vkr + 1) * LDQKV + vcol + vdc);

  for (int kt = 0; kt <= qt; ++kt) {
    const int nxt = cur ^ 1;
    if (kt < qt) {  // prefetch next K tile into other buffer
      const short* kg = base + (long)((kt + 1) * 64 + krow) * LDQKV + kcol + kc16;
      gload_lds16(kg, &Ks[nxt][(w * 16) * 64]);
      gload_lds16(kg + (long)8 * LDQKV, &Ks[nxt][(w * 16 + 8) * 64]);
    }
    __builtin_amdgcn_sched_barrier(0);
    // write V^T (tile kt); compiler's wait on va/vb also drains this tile's K
#pragma unroll
    for (int j = 0; j < 8; ++j) {
      unsigned val = (unsigned)(unsigned short)va[j] | ((unsigned)(unsigned short)vb[j] << 16);
      Vt32[vdc + j][vcol_sw] = val;
    }
    __builtin_amdgcn_sched_barrier(0);  // keep next V-reg loads after K issue + V writes
    bf16x8 van, vbn;
    if (kt < qt) {
      van = *reinterpret_cast<const bf16x8*>(base + (long)((kt + 1) * 64 + vkr) * LDQKV + vcol + vdc);
      vbn = *reinterpret_cast<const bf16x8*>(base + (long)((kt + 1) * 64 + vkr + 1) * LDQKV + vcol + vdc);
    }
    asm volatile("s_waitcnt lgkmcnt(0)" ::: "memory");
    __builtin_amdgcn_s_barrier();
    asm volatile("" ::: "memory");

    // S^T = mfma(K, Q): lane holds S[k = n*16+lk*4+j][q = lr]
    const short* Kb = &Ks[cur][0];
    f32x4 sc[4];
#pragma unroll
    for (int n = 0; n < 4; ++n) {
      const int rr = n * 16 + lr;
      bf16x8 kb0 = *reinterpret_cast<const bf16x8*>(Kb + rr * 64 + ((lk ^ (lr & 7)) * 8));
      bf16x8 kb1 = *reinterpret_cast<const bf16x8*>(Kb + rr * 64 + (((4 + lk) ^ (lr & 7)) * 8));
      f32x4 z = {};
      z = __builtin_amdgcn_mfma_f32_16x16x32_bf16(kb0, qf0, z, 0, 0, 0);
      sc[n] = __builtin_amdgcn_mfma_f32_16x16x32_bf16(kb1, qf1, z, 0, 0, 0);
    }

    const bool diag = (kt == qt);
    float lm = -1e30f;
#pragma unroll
    for (int n = 0; n < 4; ++n)
#pragma unroll
      for (int j = 0; j < 4; ++j) {
        float v = sc[n][j] * 0.25f;
        if (diag && (n * 16 + lk * 4 + j) > (w * 16 + lr)) v = -1e30f;
        sc[n][j] = v;
        lm = fmaxf(lm, v);
      }
    lm = fmaxf(lm, __shfl_xor(lm, 16));
    lm = fmaxf(lm, __shfl_xor(lm, 32));
    const float mn = fmaxf(m, lm);
    const float al = __expf(m - mn);
    m = mn;
    float ls = 0.f;
#pragma unroll
    for (int n = 0; n < 4; ++n)
#pragma unroll
      for (int j = 0; j < 4; ++j) {
        float pv = __expf(sc[n][j] - mn);
        sc[n][j] = pv;
        ls += pv;
      }
    ls += __shfl_xor(ls, 16);
    ls += __shfl_xor(ls, 32);
    lsum = lsum * al + ls;

    // pack P -> bf16 pairs, store to per-wave swizzled LDS
#pragma unroll
    for (int n = 0; n < 4; ++n)
#pragma unroll
      for (int t = 0; t < 2; ++t) {
        unsigned r;
        asm("v_cvt_pk_bf16_f32 %0, %1, %2" : "=v"(r) : "v"(sc[n][2 * t]), "v"(sc[n][2 * t + 1]));
        const int c = 8 * n + 2 * lk + t;
        Ps32[w][lr][4 * ((c >> 2) ^ (lr & 7)) + (c & 3)] = r;
      }

    // rescale O (O rows are q = lk*4+j; alpha lives at lane lr==q)
    const float a0 = __shfl(al, lk * 4 + 0), a1 = __shfl(al, lk * 4 + 1);
    const float a2 = __shfl(al, lk * 4 + 2), a3 = __shfl(al, lk * 4 + 3);
#pragma unroll
    for (int n = 0; n < 4; ++n) {
      o[n][0] *= a0; o[n][1] *= a1; o[n][2] *= a2; o[n][3] *= a3;
    }

    // PV: A = P (from LDS), B = V^T rows
#pragma unroll
    for (int ks = 0; ks < 2; ++ks) {
      bf16x8 pa = *reinterpret_cast<const bf16x8*>(&Ps32[w][lr][4 * ((4 * ks + lk) ^ (lr & 7))]);
#pragma unroll
      for (int n = 0; n < 4; ++n) {
        const int d = n * 16 + lr;
        bf16x8 vf = *reinterpret_cast<const bf16x8*>(&Vt32[d][4 * ((4 * ks + lk) ^ ((d >> 3) & 7))]);
        o[n] = __builtin_amdgcn_mfma_f32_16x16x32_bf16(pa, vf, o[n], 0, 0, 0);
      }
    }

    asm volatile("" ::: "memory");
    __builtin_amdgcn_s_barrier();   // protect Kbuf[nxt]/Vt rewrite next iter
    asm volatile("" ::: "memory");
    va = van; vb = vbn; cur = nxt;
  }

  const float inv = 1.0f / lsum;
  const float i0 = __shfl(inv, lk * 4 + 0), i1 = __shfl(inv, lk * 4 + 1);
  const float i2 = __shfl(inv, lk * 4 + 2), i3 = __shfl(inv, lk * 4 + 3);
#pragma unroll
  for (int n = 0; n < 4; ++n) {
    const int col = h * 64 + n * 16 + lr;
    const long r0 = (long)(b * TSEQ + qt * 64 + w * 16 + lk * 4) * CDIM + col;
    y[r0]            = f2bf(o[n][0] * i0);
    y[r0 + CDIM]     = f2bf(o[n][1] * i1);
    y[r0 + 2 * CDIM] = f2bf(o[n][2] * i2);
    y[r0 + 3 * CDIM] = f2bf(o[n][3] * i3);
  }
}

extern "C" void kernel_launch(void* const* d_in, const int* in_sizes, int n_in,
                              void* d_out, int out_size, void* d_ws, size_t ws_size,
                              hipStream_t stream) {
  const float* x      = (const float*)d_in[0];
  const float* w_attn = (const float*)d_in[1];
  const float* b_attn = (const float*)d_in[2];
  const float* w_proj = (const float*)d_in[3];
  const float* b_proj = (const float*)d_in[4];
  float* out = (float*)d_out;

  char* ws = (char*)d_ws;
  short* Xb   = (short*)(ws);
  short* Wab  = (short*)(ws + 12582912);
  short* Wpb  = (short*)(ws + 16121856);
  short* QKVb = (short*)(ws + 17301504);
  short* Yb   = (short*)(ws + 55050240);

  cast_bf16_kernel<<<2048, 256, 0, stream>>>(x,      Xb,  (NB * TSEQ * CDIM) / 4);
  cast_bf16_kernel<<<1728, 256, 0, stream>>>(w_attn, Wab, (3 * CDIM * CDIM) / 4);
  cast_bf16_kernel<<<576,  256, 0, stream>>>(w_proj, Wpb, (CDIM * CDIM) / 4);

  gemm_bt_kernel<1><<<dim3(64, 18), 256, 0, stream>>>(Xb, Wab, b_attn, QKVb, 8192, 2304, 768);
  attn_kernel<<<NB * NH * 32, 256, 0, stream>>>(QKVb, Yb);
  gemm_bt_kernel<0><<<dim3(64, 6), 256, 0, stream>>>(Yb, Wpb, b_proj, out, 8192, 768, 768);
}

// Round 3
// 222.267 us; speedup vs baseline: 1.6000x; 1.4116x over previous
//
#include <hip/hip_runtime.h>
#include <hip/hip_bf16.h>

#define TSEQ 2048
#define NB 4
#define NH 12
#define CDIM 768
#define LDQKV 2304

typedef short bf16x8 __attribute__((ext_vector_type(8)));
typedef float f32x4 __attribute__((ext_vector_type(4)));

__device__ __forceinline__ short f2bf(float f) {
  union { float f; unsigned u; } x; x.f = f;
  unsigned r = x.u + 0x7fffu + ((x.u >> 16) & 1u);  // RNE
  return (short)(r >> 16);
}

__device__ __forceinline__ float fexp2(float x) {
  float r; asm("v_exp_f32 %0, %1" : "=v"(r) : "v"(x)); return r;
}

__device__ __forceinline__ void gload_lds16(const void* g, void* lds) {
  __builtin_amdgcn_global_load_lds(
      (const __attribute__((address_space(1))) void*)g,
      (__attribute__((address_space(3))) void*)lds, 16, 0, 0);
}

__global__ __launch_bounds__(256) void cast_bf16_kernel(
    const float* __restrict__ in, short* __restrict__ out, int n4) {
  int i = blockIdx.x * 256 + threadIdx.x;
  const int stride = gridDim.x * 256;
  for (; i < n4; i += stride) {
    float4 v = reinterpret_cast<const float4*>(in)[i];
    short4 r = make_short4(f2bf(v.x), f2bf(v.y), f2bf(v.z), f2bf(v.w));
    reinterpret_cast<short4*>(out)[i] = r;
  }
}

// C[M,N] = A[M,K] * B[N,K]^T + bias.  m97 structure + bijective XCD swizzle.
template<int OUTBF>
__global__ __launch_bounds__(256) void gemm_bt_kernel(
    const short* __restrict__ A, const short* __restrict__ B,
    const float* __restrict__ bias, void* __restrict__ C,
    int M, int N, int K) {
  __shared__ __align__(16) short As[128 * 32];
  __shared__ __align__(16) short Bs[128 * 32];
  const int tid = threadIdx.x;
  const int w = tid >> 6, l = tid & 63;
  const int lr = l & 15, lk = l >> 4;
  const int nwg = gridDim.x * gridDim.y;
  const int wg = blockIdx.y * gridDim.x + blockIdx.x;
  const int swz = (wg & 7) * (nwg >> 3) + (wg >> 3);
  const int bm = (swz % gridDim.x) * 128, bn = (swz / gridDim.x) * 128;
  const int wr = (w >> 1) * 64, wc = (w & 1) * 64;
  const int srow = tid >> 2, scol = (tid & 3) * 8;

  const short* Ag = A + (long)(bm + srow) * K + scol;
  const short* Bg = B + (long)(bn + srow) * K + scol;
  short* AsW = As + w * 512;
  short* BsW = Bs + w * 512;

  f32x4 acc[4][4] = {};

  for (int kk = 0; kk < K; kk += 32) {
    gload_lds16(Ag + kk, AsW);
    gload_lds16(Ag + (long)64 * K + kk, AsW + 2048);
    gload_lds16(Bg + kk, BsW);
    gload_lds16(Bg + (long)64 * K + kk, BsW + 2048);
    __syncthreads();
    bf16x8 af[4], bfr[4];
#pragma unroll
    for (int m = 0; m < 4; ++m)
      af[m] = *reinterpret_cast<const bf16x8*>(As + (wr + m * 16 + lr) * 32 + lk * 8);
#pragma unroll
    for (int n = 0; n < 4; ++n)
      bfr[n] = *reinterpret_cast<const bf16x8*>(Bs + (wc + n * 16 + lr) * 32 + lk * 8);
#pragma unroll
    for (int m = 0; m < 4; ++m)
#pragma unroll
      for (int n = 0; n < 4; ++n)
        acc[m][n] = __builtin_amdgcn_mfma_f32_16x16x32_bf16(af[m], bfr[n], acc[m][n], 0, 0, 0);
    __syncthreads();
  }

  float bv[4];
#pragma unroll
  for (int n = 0; n < 4; ++n) bv[n] = bias[bn + wc + n * 16 + lr];
#pragma unroll
  for (int m = 0; m < 4; ++m) {
    const int row0 = bm + wr + m * 16 + lk * 4;
#pragma unroll
    for (int n = 0; n < 4; ++n) {
      const int col = bn + wc + n * 16 + lr;
#pragma unroll
      for (int j = 0; j < 4; ++j) {
        float v = acc[m][n][j] + bv[n];
        if (OUTBF) reinterpret_cast<short*>(C)[(long)(row0 + j) * N + col] = f2bf(v);
        else       reinterpret_cast<float*>(C)[(long)(row0 + j) * N + col] = v;
      }
    }
  }
}

// Flash attention v3: paired q-tiles (qt, 31-qt) for uniform work; XCD-swizzled
// grid (768 = 8*96, 6 heads/XCD so K/V are L2-resident); swapped QK^T; K
// double-buffered via swizzled-source global_load_lds; V/P packed b32, P at
// stride-32 XOR layout (bank-floor); base-2 softmax w/ defer-max THR=8.
__global__ __launch_bounds__(256) void attn_kernel(
    const short* __restrict__ qkv, short* __restrict__ y) {
  __shared__ __align__(16) short    Ks[2][64 * 64];
  __shared__ __align__(16) unsigned Vt32[64][36];
  __shared__ __align__(16) unsigned Ps32[4][16][32];
  const int tid = threadIdx.x;
  const int w = tid >> 6, l = tid & 63;
  const int lr = l & 15, lk = l >> 4;
  const int bid = blockIdx.x;
  const int swz = (bid & 7) * 96 + (bid >> 3);   // 768 = 8 XCD * 96
  const int ti = swz & 15;
  const int bh = swz >> 4;
  const int b = bh / NH, h = bh % NH;
  const short* base = qkv + (long)b * TSEQ * LDQKV;
  const int kcol = h * 64, qcol = CDIM + h * 64, vcol = 2 * CDIM + h * 64;
  const float SCL = 0.36067376022224085f;  // 0.25 * log2(e)

  const int krow = w * 16 + (l >> 3);
  const int kc16 = (((l & 7) ^ (l >> 3)) * 8);
  const int vkr = (tid >> 3) * 2;
  const int vdc = (tid & 7) * 8;
  const int vc = tid >> 3;
  const int vcol_sw = 4 * ((vc >> 2) ^ (tid & 7)) + (vc & 3);

#pragma unroll 1
  for (int pp = 0; pp < 2; ++pp) {
    const int qt = pp ? (31 - ti) : ti;

    const int qrow = qt * 64 + w * 16 + lr;
    bf16x8 qf0 = *reinterpret_cast<const bf16x8*>(base + (long)qrow * LDQKV + qcol + lk * 8);
    bf16x8 qf1 = *reinterpret_cast<const bf16x8*>(base + (long)qrow * LDQKV + qcol + 32 + lk * 8);

    float m = -1e30f, lsum = 0.f;
    f32x4 o[4] = {};
    int cur = 0;
    {
      const short* kg = base + (long)krow * LDQKV + kcol + kc16;
      gload_lds16(kg, &Ks[0][(w * 16) * 64]);
      gload_lds16(kg + (long)8 * LDQKV, &Ks[0][(w * 16 + 8) * 64]);
    }
    __builtin_amdgcn_sched_barrier(0);
    bf16x8 va = *reinterpret_cast<const bf16x8*>(base + (long)vkr * LDQKV + vcol + vdc);
    bf16x8 vb = *reinterpret_cast<const bf16x8*>(base + (long)(vkr + 1) * LDQKV + vcol + vdc);

    for (int kt = 0; kt <= qt; ++kt) {
      const int nxt = cur ^ 1;
      if (kt < qt) {
        const short* kg = base + (long)((kt + 1) * 64 + krow) * LDQKV + kcol + kc16;
        gload_lds16(kg, &Ks[nxt][(w * 16) * 64]);
        gload_lds16(kg + (long)8 * LDQKV, &Ks[nxt][(w * 16 + 8) * 64]);
      }
      __builtin_amdgcn_sched_barrier(0);
      // write V^T (tile kt); implicit vmcnt wait on va/vb also drains K(kt)
#pragma unroll
      for (int j = 0; j < 8; ++j) {
        unsigned val = (unsigned)(unsigned short)va[j] | ((unsigned)(unsigned short)vb[j] << 16);
        Vt32[vdc + j][vcol_sw] = val;
      }
      __builtin_amdgcn_sched_barrier(0);
      bf16x8 van, vbn;
      if (kt < qt) {
        van = *reinterpret_cast<const bf16x8*>(base + (long)((kt + 1) * 64 + vkr) * LDQKV + vcol + vdc);
        vbn = *reinterpret_cast<const bf16x8*>(base + (long)((kt + 1) * 64 + vkr + 1) * LDQKV + vcol + vdc);
      }
      asm volatile("s_waitcnt lgkmcnt(0)" ::: "memory");
      __builtin_amdgcn_s_barrier();
      asm volatile("" ::: "memory");

      // S^T = mfma(K, Q): lane holds S[k = n*16+lk*4+j][q = lr]
      const short* Kb = &Ks[cur][0];
      f32x4 sc[4];
      __builtin_amdgcn_s_setprio(1);
#pragma unroll
      for (int n = 0; n < 4; ++n) {
        const int rr = n * 16 + lr;
        bf16x8 kb0 = *reinterpret_cast<const bf16x8*>(Kb + rr * 64 + ((lk ^ (lr & 7)) * 8));
        bf16x8 kb1 = *reinterpret_cast<const bf16x8*>(Kb + rr * 64 + (((4 + lk) ^ (lr & 7)) * 8));
        f32x4 z = {};
        z = __builtin_amdgcn_mfma_f32_16x16x32_bf16(kb0, qf0, z, 0, 0, 0);
        sc[n] = __builtin_amdgcn_mfma_f32_16x16x32_bf16(kb1, qf1, z, 0, 0, 0);
      }
      __builtin_amdgcn_s_setprio(0);

      const bool diag = (kt == qt);
      float lm = -1e30f;
#pragma unroll
      for (int n = 0; n < 4; ++n)
#pragma unroll
        for (int j = 0; j < 4; ++j) {
          float v = sc[n][j] * SCL;
          if (diag && (n * 16 + lk * 4 + j) > (w * 16 + lr)) v = -1e30f;
          sc[n][j] = v;
          lm = fmaxf(lm, v);
        }
      lm = fmaxf(lm, __shfl_xor(lm, 16));
      lm = fmaxf(lm, __shfl_xor(lm, 32));

      float al = 1.0f;
      if (__any(lm > m + 8.f)) {   // defer-max (T13): skip rescale on small growth
        const float mn = fmaxf(m, lm);
        al = fexp2(m - mn);
        m = mn;
        const float a0 = __shfl(al, lk * 4 + 0), a1 = __shfl(al, lk * 4 + 1);
        const float a2 = __shfl(al, lk * 4 + 2), a3 = __shfl(al, lk * 4 + 3);
#pragma unroll
        for (int n = 0; n < 4; ++n) {
          o[n][0] *= a0; o[n][1] *= a1; o[n][2] *= a2; o[n][3] *= a3;
        }
      }

      float ls = 0.f;
#pragma unroll
      for (int n = 0; n < 4; ++n)
#pragma unroll
        for (int t = 0; t < 2; ++t) {
          float p0 = fexp2(sc[n][2 * t]     - m);
          float p1 = fexp2(sc[n][2 * t + 1] - m);
          ls += p0 + p1;
          unsigned r;
          asm("v_cvt_pk_bf16_f32 %0, %1, %2" : "=v"(r) : "v"(p0), "v"(p1));
          const int c = 8 * n + 2 * lk + t;
          Ps32[w][lr][4 * ((c >> 2) ^ (lr & 7)) + (c & 3)] = r;
        }
      ls += __shfl_xor(ls, 16);
      ls += __shfl_xor(ls, 32);
      lsum = lsum * al + ls;

      // PV: A = P, B = V^T rows
      __builtin_amdgcn_s_setprio(1);
#pragma unroll
      for (int ks = 0; ks < 2; ++ks) {
        bf16x8 pa = *reinterpret_cast<const bf16x8*>(&Ps32[w][lr][4 * ((4 * ks + lk) ^ (lr & 7))]);
#pragma unroll
        for (int n = 0; n < 4; ++n) {
          const int d = n * 16 + lr;
          bf16x8 vf = *reinterpret_cast<const bf16x8*>(&Vt32[d][4 * ((4 * ks + lk) ^ ((d >> 3) & 7))]);
          o[n] = __builtin_amdgcn_mfma_f32_16x16x32_bf16(pa, vf, o[n], 0, 0, 0);
        }
      }
      __builtin_amdgcn_s_setprio(0);

      asm volatile("" ::: "memory");
      __builtin_amdgcn_s_barrier();   // protect Ks[nxt]/Vt rewrite next iter
      asm volatile("" ::: "memory");
      va = van; vb = vbn; cur = nxt;
    }

    const float inv = 1.0f / lsum;
    const float i0 = __shfl(inv, lk * 4 + 0), i1 = __shfl(inv, lk * 4 + 1);
    const float i2 = __shfl(inv, lk * 4 + 2), i3 = __shfl(inv, lk * 4 + 3);
#pragma unroll
    for (int n = 0; n < 4; ++n) {
      const int col = h * 64 + n * 16 + lr;
      const long r0 = (long)(b * TSEQ + qt * 64 + w * 16 + lk * 4) * CDIM + col;
      y[r0]            = f2bf(o[n][0] * i0);
      y[r0 + CDIM]     = f2bf(o[n][1] * i1);
      y[r0 + 2 * CDIM] = f2bf(o[n][2] * i2);
      y[r0 + 3 * CDIM] = f2bf(o[n][3] * i3);
    }
  }
}

extern "C" void kernel_launch(void* const* d_in, const int* in_sizes, int n_in,
                              void* d_out, int out_size, void* d_ws, size_t ws_size,
                              hipStream_t stream) {
  const float* x      = (const float*)d_in[0];
  const float* w_attn = (const float*)d_in[1];
  const float* b_attn = (const float*)d_in[2];
  const float* w_proj = (const float*)d_in[3];
  const float* b_proj = (const float*)d_in[4];
  float* out = (float*)d_out;

  char* ws = (char*)d_ws;
  short* Xb   = (short*)(ws);
  short* Wab  = (short*)(ws + 12582912);
  short* Wpb  = (short*)(ws + 16121856);
  short* QKVb = (short*)(ws + 17301504);
  short* Yb   = (short*)(ws + 55050240);

  cast_bf16_kernel<<<2048, 256, 0, stream>>>(x,      Xb,  (NB * TSEQ * CDIM) / 4);
  cast_bf16_kernel<<<1728, 256, 0, stream>>>(w_attn, Wab, (3 * CDIM * CDIM) / 4);
  cast_bf16_kernel<<<576,  256, 0, stream>>>(w_proj, Wpb, (CDIM * CDIM) / 4);

  gemm_bt_kernel<1><<<dim3(64, 18), 256, 0, stream>>>(Xb, Wab, b_attn, QKVb, 8192, 2304, 768);
  attn_kernel<<<NB * NH * 16, 256, 0, stream>>>(QKVb, Yb);
  gemm_bt_kernel<0><<<dim3(64, 6), 256, 0, stream>>>(Yb, Wpb, b_proj, out, 8192, 768, 768);
}

// Round 4
// 215.053 us; speedup vs baseline: 1.6537x; 1.0335x over previous
//
#include <hip/hip_runtime.h>
#include <hip/hip_bf16.h>

#define TSEQ 2048
#define NB 4
#define NH 12
#define CDIM 768

typedef short bf16x8 __attribute__((ext_vector_type(8)));
typedef float f32x4 __attribute__((ext_vector_type(4)));

__device__ __forceinline__ short f2bf(float f) {
  union { float f; unsigned u; } x; x.f = f;
  unsigned r = x.u + 0x7fffu + ((x.u >> 16) & 1u);  // RNE
  return (short)(r >> 16);
}

__device__ __forceinline__ float fexp2(float x) {
  float r; asm("v_exp_f32 %0, %1" : "=v"(r) : "v"(x)); return r;
}

__device__ __forceinline__ void gload_lds16(const void* g, void* lds) {
  __builtin_amdgcn_global_load_lds(
      (const __attribute__((address_space(1))) void*)g,
      (__attribute__((address_space(3))) void*)lds, 16, 0, 0);
}

// fused fp32->bf16 cast for x, w_attn, w_proj
__global__ __launch_bounds__(256) void cast3_kernel(
    const float* __restrict__ x, const float* __restrict__ wa,
    const float* __restrict__ wp, short* __restrict__ xb,
    short* __restrict__ wab, short* __restrict__ wpb,
    int n0, int n1, int n2) {
  int i = blockIdx.x * 256 + threadIdx.x;
  const int total = n0 + n1 + n2;
  const int stride = gridDim.x * 256;
  for (; i < total; i += stride) {
    const float* src; short* dst; int j = i;
    if (j < n0)            { src = x;  dst = xb; }
    else if (j < n0 + n1)  { j -= n0; src = wa; dst = wab; }
    else                   { j -= n0 + n1; src = wp; dst = wpb; }
    float4 v = reinterpret_cast<const float4*>(src)[j];
    reinterpret_cast<short4*>(dst)[j] =
        make_short4(f2bf(v.x), f2bf(v.y), f2bf(v.z), f2bf(v.w));
  }
}

// C = A[M,K] * B[N,K]^T + bias. 128x128 tile, BK=32, dbuf LDS, 1 barrier/step,
// vmcnt waited one step late. MODE 0: fp32 -> C0 (ld N).
// MODE 2 (qkv split, N=2304): cols [0,768)->Kb bf16; [768,1536)->Qb bf16
// scaled by 0.25*log2(e); [1536,2304)->V^T bf16 at C2[((b*12+h)*64+d)*2048+t].
template<int MODE>
__global__ __launch_bounds__(256) void gemm_bt_kernel(
    const short* __restrict__ A, const short* __restrict__ B,
    const float* __restrict__ bias, void* __restrict__ C0,
    void* __restrict__ C1, void* __restrict__ C2,
    int M, int N, int K) {
  __shared__ __align__(16) short As[2][4096];
  __shared__ __align__(16) short Bs[2][4096];
  const int tid = threadIdx.x;
  const int w = tid >> 6, l = tid & 63;
  const int lr = l & 15, lk = l >> 4;
  const int nwg = gridDim.x * gridDim.y;
  const int wg = blockIdx.y * gridDim.x + blockIdx.x;
  const int swz = (wg & 7) * (nwg >> 3) + (wg >> 3);
  const int bm = (swz % gridDim.x) * 128, bn = (swz / gridDim.x) * 128;
  const int wr = (w >> 1) * 64, wc = (w & 1) * 64;
  const int srow = tid >> 2, scol = (tid & 3) * 8;

  const short* Ag = A + (long)(bm + srow) * K + scol;
  const short* Bg = B + (long)(bn + srow) * K + scol;

  f32x4 acc[4][4] = {};
  int cur = 0;
  // prologue: stage K-step 0 into buf 0
  gload_lds16(Ag, &As[0][w * 512]);
  gload_lds16(Ag + (long)64 * K, &As[0][2048 + w * 512]);
  gload_lds16(Bg, &Bs[0][w * 512]);
  gload_lds16(Bg + (long)64 * K, &Bs[0][2048 + w * 512]);

  for (int kk = 0; kk < K; kk += 32) {
    asm volatile("s_waitcnt vmcnt(0)" ::: "memory");
    __builtin_amdgcn_s_barrier();
    asm volatile("" ::: "memory");
    if (kk + 32 < K) {
      const int nxt = cur ^ 1;
      gload_lds16(Ag + kk + 32, &As[nxt][w * 512]);
      gload_lds16(Ag + (long)64 * K + kk + 32, &As[nxt][2048 + w * 512]);
      gload_lds16(Bg + kk + 32, &Bs[nxt][w * 512]);
      gload_lds16(Bg + (long)64 * K + kk + 32, &Bs[nxt][2048 + w * 512]);
    }
    __builtin_amdgcn_sched_barrier(0);
    bf16x8 af[4], bfr[4];
#pragma unroll
    for (int m = 0; m < 4; ++m)
      af[m] = *reinterpret_cast<const bf16x8*>(&As[cur][(wr + m * 16 + lr) * 32 + lk * 8]);
#pragma unroll
    for (int n = 0; n < 4; ++n)
      bfr[n] = *reinterpret_cast<const bf16x8*>(&Bs[cur][(wc + n * 16 + lr) * 32 + lk * 8]);
    __builtin_amdgcn_s_setprio(1);
#pragma unroll
    for (int m = 0; m < 4; ++m)
#pragma unroll
      for (int n = 0; n < 4; ++n)
        acc[m][n] = __builtin_amdgcn_mfma_f32_16x16x32_bf16(af[m], bfr[n], acc[m][n], 0, 0, 0);
    __builtin_amdgcn_s_setprio(0);
    cur ^= 1;
  }

  float bv[4];
#pragma unroll
  for (int n = 0; n < 4; ++n) bv[n] = bias[bn + wc + n * 16 + lr];

  if (MODE == 0) {
#pragma unroll
    for (int m = 0; m < 4; ++m) {
      const int row0 = bm + wr + m * 16 + lk * 4;
#pragma unroll
      for (int n = 0; n < 4; ++n) {
        const int col = bn + wc + n * 16 + lr;
#pragma unroll
        for (int j = 0; j < 4; ++j)
          reinterpret_cast<float*>(C0)[(long)(row0 + j) * N + col] = acc[m][n][j] + bv[n];
      }
    }
  } else {
    const int reg_ = bn / 768;
    const int cb = bn - reg_ * 768;
    if (reg_ < 2) {
      short* dst = (short*)(reg_ ? C1 : C0);
      const float s = reg_ ? 0.36067376022224085f : 1.0f;  // Q: 0.25*log2(e)
#pragma unroll
      for (int m = 0; m < 4; ++m) {
        const int row0 = bm + wr + m * 16 + lk * 4;
#pragma unroll
        for (int n = 0; n < 4; ++n) {
          const int col = cb + wc + n * 16 + lr;
#pragma unroll
          for (int j = 0; j < 4; ++j)
            dst[(long)(row0 + j) * 768 + col] = f2bf((acc[m][n][j] + bv[n]) * s);
        }
      }
    } else {
      short* dst = (short*)C2;
#pragma unroll
      for (int m = 0; m < 4; ++m) {
        const int row0 = bm + wr + m * 16 + lk * 4;
        const int b_ = row0 >> 11, t0 = row0 & 2047;
#pragma unroll
        for (int n = 0; n < 4; ++n) {
          const int c = cb + wc + n * 16 + lr;
          short4 pk4 = make_short4(f2bf(acc[m][n][0] + bv[n]), f2bf(acc[m][n][1] + bv[n]),
                                   f2bf(acc[m][n][2] + bv[n]), f2bf(acc[m][n][3] + bv[n]));
          *reinterpret_cast<short4*>(dst + (long)((b_ * NH + (c >> 6)) * 64 + (c & 63)) * TSEQ + t0) = pk4;
        }
      }
    }
  }
}

// Flash attention v4: K and V^T both staged via swizzled-source global_load_lds
// (dbuf, 1 barrier/iter, vmcnt waited an iter late); swapped QK^T (S^T);
// scale pre-folded into Q (exp2 domain); row-sum via ones-column MFMA (o5);
// P packed ds_write_b64 at bank floor; defer-max THR=8 (log2).
__global__ __launch_bounds__(256) void attn_kernel(
    const short* __restrict__ Kg, const short* __restrict__ Qg,
    const short* __restrict__ Vtg, short* __restrict__ y) {
  __shared__ __align__(16) short Ks[2][4096];
  __shared__ __align__(16) short Vts[2][4096];
  __shared__ __align__(16) unsigned Ps32[4][16][32];
  const int tid = threadIdx.x;
  const int w = tid >> 6, l = tid & 63;
  const int lr = l & 15, lk = l >> 4;
  const int bid = blockIdx.x;
  const int swz = (bid & 7) * 96 + (bid >> 3);   // 768 = 8 XCD * 96
  const int ti = swz & 15;
  const int bh = swz >> 4;
  const int b = bh / NH, h = bh % NH;
  const short* Kbase = Kg + (long)b * TSEQ * CDIM + h * 64;
  const short* Qbase = Qg + (long)b * TSEQ * CDIM + h * 64;
  const short* Vbase = Vtg + (long)(b * NH + h) * 64 * TSEQ;
  const int sr = l >> 3;                  // staging row within 8-row group
  const int sc16 = ((l & 7) ^ sr) * 8;    // pre-swizzled source col (shorts)
  const short ONE = 0x3F80;               // bf16 1.0
  const bf16x8 ones = {ONE, ONE, ONE, ONE, ONE, ONE, ONE, ONE};

#pragma unroll 1
  for (int pp = 0; pp < 2; ++pp) {
    const int qt = pp ? (31 - ti) : ti;
    const int qrow = qt * 64 + w * 16 + lr;
    bf16x8 qf0 = *reinterpret_cast<const bf16x8*>(Qbase + (long)qrow * CDIM + lk * 8);
    bf16x8 qf1 = *reinterpret_cast<const bf16x8*>(Qbase + (long)qrow * CDIM + 32 + lk * 8);

    float m = -1e30f;
    f32x4 o[4] = {};
    f32x4 o5 = {};
    int cur = 0;

    if (pp) { __builtin_amdgcn_s_barrier(); asm volatile("" ::: "memory"); }
    {
      const short* kg = Kbase + (long)(w * 16 + sr) * CDIM + sc16;
      gload_lds16(kg, &Ks[0][(w * 16) * 64]);
      gload_lds16(kg + (long)8 * CDIM, &Ks[0][(w * 16 + 8) * 64]);
      const short* vg = Vbase + (long)(w * 16 + sr) * TSEQ + sc16;
      gload_lds16(vg, &Vts[0][(w * 16) * 64]);
      gload_lds16(vg + (long)8 * TSEQ, &Vts[0][(w * 16 + 8) * 64]);
    }

    for (int kt = 0; kt <= qt; ++kt) {
      asm volatile("s_waitcnt vmcnt(0)" ::: "memory");
      __builtin_amdgcn_s_barrier();
      asm volatile("" ::: "memory");
      if (kt < qt) {
        const int nxt = cur ^ 1;
        const short* kg = Kbase + (long)((kt + 1) * 64 + w * 16 + sr) * CDIM + sc16;
        gload_lds16(kg, &Ks[nxt][(w * 16) * 64]);
        gload_lds16(kg + (long)8 * CDIM, &Ks[nxt][(w * 16 + 8) * 64]);
        const short* vg = Vbase + (long)(w * 16 + sr) * TSEQ + (kt + 1) * 64 + sc16;
        gload_lds16(vg, &Vts[nxt][(w * 16) * 64]);
        gload_lds16(vg + (long)8 * TSEQ, &Vts[nxt][(w * 16 + 8) * 64]);
      }
      __builtin_amdgcn_sched_barrier(0);

      const short* Kb = &Ks[cur][0];
      const short* Vb = &Vts[cur][0];
      f32x4 sc[4];
      __builtin_amdgcn_s_setprio(1);
#pragma unroll
      for (int n = 0; n < 4; ++n) {
        const int rr = n * 16 + lr;
        bf16x8 kb0 = *reinterpret_cast<const bf16x8*>(Kb + rr * 64 + ((lk ^ (lr & 7)) * 8));
        bf16x8 kb1 = *reinterpret_cast<const bf16x8*>(Kb + rr * 64 + (((4 + lk) ^ (lr & 7)) * 8));
        f32x4 z = {};
        z = __builtin_amdgcn_mfma_f32_16x16x32_bf16(kb0, qf0, z, 0, 0, 0);
        sc[n] = __builtin_amdgcn_mfma_f32_16x16x32_bf16(kb1, qf1, z, 0, 0, 0);
      }
      __builtin_amdgcn_s_setprio(0);

      if (kt == qt) {
#pragma unroll
        for (int n = 0; n < 4; ++n)
#pragma unroll
          for (int j = 0; j < 4; ++j)
            if ((n * 16 + lk * 4 + j) > (w * 16 + lr)) sc[n][j] = -1e30f;
      }

      float lm = -1e30f;
#pragma unroll
      for (int n = 0; n < 4; ++n)
        lm = fmaxf(lm, fmaxf(fmaxf(sc[n][0], sc[n][1]), fmaxf(sc[n][2], sc[n][3])));
      lm = fmaxf(lm, __shfl_xor(lm, 16));
      lm = fmaxf(lm, __shfl_xor(lm, 32));

      if (__any(lm > m + 8.f)) {        // defer-max (exp2 domain)
        const float mn = fmaxf(m, lm);
        const float al = fexp2(m - mn);
        m = mn;
        const float a0 = __shfl(al, lk * 4 + 0), a1 = __shfl(al, lk * 4 + 1);
        const float a2 = __shfl(al, lk * 4 + 2), a3 = __shfl(al, lk * 4 + 3);
#pragma unroll
        for (int n = 0; n < 4; ++n) {
          o[n][0] *= a0; o[n][1] *= a1; o[n][2] *= a2; o[n][3] *= a3;
        }
        o5[0] *= a0; o5[1] *= a1; o5[2] *= a2; o5[3] *= a3;
      }

      // P = exp2(S - m), pack pairs, b64 store (bank-floor layout)
#pragma unroll
      for (int n = 0; n < 4; ++n) {
        float p0 = fexp2(sc[n][0] - m), p1 = fexp2(sc[n][1] - m);
        float p2 = fexp2(sc[n][2] - m), p3 = fexp2(sc[n][3] - m);
        unsigned r0, r1;
        asm("v_cvt_pk_bf16_f32 %0, %1, %2" : "=v"(r0) : "v"(p0), "v"(p1));
        asm("v_cvt_pk_bf16_f32 %0, %1, %2" : "=v"(r1) : "v"(p2), "v"(p3));
        uint2 vv; vv.x = r0; vv.y = r1;
        // kp = 8n+2lk+t: granule u=2n+(lk>>1), offs 2*(lk&1)
        *reinterpret_cast<uint2*>(
            &Ps32[w][lr][4 * ((2 * n + (lk >> 1)) ^ (lr & 7)) + 2 * (lk & 1)]) = vv;
      }

      __builtin_amdgcn_s_setprio(1);
#pragma unroll
      for (int ks = 0; ks < 2; ++ks) {
        bf16x8 pa = *reinterpret_cast<const bf16x8*>(
            &Ps32[w][lr][4 * ((ks * 4 + lk) ^ (lr & 7))]);
        o5 = __builtin_amdgcn_mfma_f32_16x16x32_bf16(pa, ones, o5, 0, 0, 0);
#pragma unroll
        for (int n = 0; n < 4; ++n) {
          const int rr = n * 16 + lr;
          bf16x8 vf = *reinterpret_cast<const bf16x8*>(
              Vb + rr * 64 + (((ks * 4 + lk) ^ (lr & 7)) * 8));
          o[n] = __builtin_amdgcn_mfma_f32_16x16x32_bf16(pa, vf, o[n], 0, 0, 0);
        }
      }
      __builtin_amdgcn_s_setprio(0);
      cur ^= 1;
    }

    const float i0 = 1.0f / o5[0], i1 = 1.0f / o5[1];
    const float i2 = 1.0f / o5[2], i3 = 1.0f / o5[3];
#pragma unroll
    for (int n = 0; n < 4; ++n) {
      const int col = h * 64 + n * 16 + lr;
      const long r0 = (long)(b * TSEQ + qt * 64 + w * 16 + lk * 4) * CDIM + col;
      y[r0]            = f2bf(o[n][0] * i0);
      y[r0 + CDIM]     = f2bf(o[n][1] * i1);
      y[r0 + 2 * CDIM] = f2bf(o[n][2] * i2);
      y[r0 + 3 * CDIM] = f2bf(o[n][3] * i3);
    }
  }
}

extern "C" void kernel_launch(void* const* d_in, const int* in_sizes, int n_in,
                              void* d_out, int out_size, void* d_ws, size_t ws_size,
                              hipStream_t stream) {
  const float* x      = (const float*)d_in[0];
  const float* w_attn = (const float*)d_in[1];
  const float* b_attn = (const float*)d_in[2];
  const float* w_proj = (const float*)d_in[3];
  const float* b_proj = (const float*)d_in[4];
  float* out = (float*)d_out;

  char* ws = (char*)d_ws;
  short* Xb  = (short*)(ws);              // 12,582,912 B
  short* Wab = (short*)(ws + 12582912);   //  3,538,944 B
  short* Wpb = (short*)(ws + 16121856);   //  1,179,648 B
  short* Kb  = (short*)(ws + 17301504);   // 12,582,912 B
  short* Qb  = (short*)(ws + 29884416);   // 12,582,912 B
  short* VtG = (short*)(ws + 42467328);   // 12,582,912 B
  short* Yb  = (short*)(ws + 55050240);   // 12,582,912 B

  const int n0 = NB * TSEQ * CDIM / 4, n1 = 3 * CDIM * CDIM / 4, n2 = CDIM * CDIM / 4;
  cast3_kernel<<<2048, 256, 0, stream>>>(x, w_attn, w_proj, Xb, Wab, Wpb, n0, n1, n2);

  gemm_bt_kernel<2><<<dim3(64, 18), 256, 0, stream>>>(Xb, Wab, b_attn, Kb, Qb, VtG, 8192, 2304, 768);
  attn_kernel<<<NB * NH * 16, 256, 0, stream>>>(Kb, Qb, VtG, Yb);
  gemm_bt_kernel<0><<<dim3(64, 6), 256, 0, stream>>>(Yb, Wpb, b_proj, out, nullptr, nullptr, 8192, 768, 768);
}